// Round 14
// baseline (258.924 us; speedup 1.0000x reference)
//
#include <hip/hip_runtime.h>

#define E 4096
#define H 32
#define L 8192
#define SCALE 0.08838834764831845f  // 1/sqrt(128)

// workspace layout (float offsets); total 734208 floats = 2.9 MB
#define WS_PART  0            // [3][32][4096] exclusive qkv partials
#define WS_QFIN  393216       // 4096 (bias included)
#define WS_KFIN  397312       // 4096 (bias included)
#define WS_VFIN  401408       // 4096 (bias included)
#define WS_NUMP  405504       // 16 reps x 4096 (zeroed)
#define WS_DENP  471040       // 16 reps x 64   (zeroed)
#define WS_OPART 472064       // [64][4096] exclusive gemv_out partials

typedef float fv4 __attribute__((ext_vector_type(4)));

__device__ __forceinline__ fv4 ntload4(const float* p) {
  return __builtin_nontemporal_load(reinterpret_cast<const fv4*>(p));
}
__device__ __forceinline__ void ntstore4(float* p, fv4 v) {
  __builtin_nontemporal_store(v, reinterpret_cast<fv4*>(p));
}

// ---------------- K0: zero NUMP/DENP only (66560 floats) --------------------
__global__ __launch_bounds__(256) void zero_np(float* __restrict__ ws) {
  int i = blockIdx.x * 256 + threadIdx.x;
  if (i < (WS_OPART - WS_NUMP)) ws[WS_NUMP + i] = 0.f;
}

// ---------------- K1: q/k/v GEMV, exclusive NT partials (no atomics) --------
__global__ __launch_bounds__(256) void gemv_qkv(const float* __restrict__ x,
    const float* __restrict__ Wq, const float* __restrict__ Wk,
    const float* __restrict__ Wv, float* __restrict__ ws) {
  int b = blockIdx.x;            // 384 blocks: 3 mats x 32 chunks x 4 col-groups
  int mat = b >> 7;
  int rem = b & 127;
  int chunk = rem >> 2;          // 32 chunks of 128 rows
  int g = rem & 3;               // 4 col groups of 1024
  const float* W = (mat == 0) ? Wq : (mat == 1) ? Wk : Wv;
  int t = threadIdx.x;
  int j = (g << 10) + (t << 2);
  float ax = 0.f, ay = 0.f, az = 0.f, aw = 0.f;
  int i0 = chunk << 7;
  #pragma unroll 8
  for (int r = 0; r < 128; ++r) {
    int i = i0 + r;
    float xi = x[i];
    const fv4 w4 = ntload4(W + (size_t)i * E + j);
    ax += xi * w4.x; ay += xi * w4.y; az += xi * w4.z; aw += xi * w4.w;
  }
  fv4 val = {ax, ay, az, aw};
  ntstore4(ws + WS_PART + (mat << 17) + (chunk << 12) + j, val);
}

// ---------------- K2: reduce 32 chunk-partials, fold in biases --------------
__global__ __launch_bounds__(256) void qkvred(const float* __restrict__ bq,
    const float* __restrict__ bk, const float* __restrict__ bv,
    float* __restrict__ ws) {
  int e = blockIdx.x * 256 + threadIdx.x;   // 48 blocks, e in [0,12288)
  int mat = e >> 12;
  int col = e & 4095;
  const float* part = ws + WS_PART + (mat << 17);
  float s = 0.f;
  #pragma unroll 8
  for (int c = 0; c < 32; ++c) s += part[(c << 12) + col];
  const float* bias = (mat == 0) ? bq : (mat == 1) ? bk : bv;
  ws[WS_QFIN + (mat << 12) + col] = s + bias[col];
}

// ---------------- K3: READ-ONLY attention pass (no cache stores) ------------
// Plain loads (warm L3 for the following D2D blit copies). Structure = R13
// kvpass minus the kout/vout stores.
#define SLOTS 16
__device__ __forceinline__ void load_slot(int o, int t,
    const float* __restrict__ kin, const float* __restrict__ vin,
    const float* __restrict__ ws, fv4 k4[4], fv4 v4[4]) {
  if (o < L - 1) {
    const float* ks = kin + (size_t)(o + 1) * E;
    const float* vs = vin + (size_t)(o + 1) * E;
    #pragma unroll
    for (int c = 0; c < 4; ++c) {
      int e = (c << 10) + (t << 2);
      k4[c] = *reinterpret_cast<const fv4*>(ks + e);
      v4[c] = *reinterpret_cast<const fv4*>(vs + e);
    }
  } else {
    #pragma unroll
    for (int c = 0; c < 4; ++c) {
      int e = (c << 10) + (t << 2);
      k4[c] = *reinterpret_cast<const fv4*>(ws + WS_KFIN + e);
      v4[c] = *reinterpret_cast<const fv4*>(ws + WS_VFIN + e);
    }
  }
}

__global__ __launch_bounds__(256) void attn(const float* __restrict__ kin,
    const float* __restrict__ vin, float* __restrict__ ws) {
  __shared__ float wlds[SLOTS * 32];
  __shared__ int flags[SLOTS];
  int t = threadIdx.x;
  if (t < SLOTS) flags[t] = 0;
  // q in registers (bias already folded in by qkvred)
  fv4 q4[4];
  #pragma unroll
  for (int c = 0; c < 4; ++c)
    q4[c] = *reinterpret_cast<const fv4*>(ws + WS_QFIN + (c << 10) + (t << 2));
  __syncthreads();   // flags init visible

  float accx[4] = {0,0,0,0}, accy[4] = {0,0,0,0};
  float accz[4] = {0,0,0,0}, accw[4] = {0,0,0,0};
  int base = blockIdx.x * SLOTS;
  int rep = blockIdx.x & 15;

  fv4 kc[4], vc[4], kn[4], vn[4];
  load_slot(base, t, kin, vin, ws, kc, vc);

  for (int s = 0; s < SLOTS; ++s) {
    int o = base + s;
    if (s + 1 < SLOTS)
      load_slot(o + 1, t, kin, vin, ws, kn, vn);
    bool nz = false;
    #pragma unroll
    for (int c = 0; c < 4; ++c) {
      float pp = kc[c].x * q4[c].x + kc[c].y * q4[c].y +
                 kc[c].z * q4[c].z + kc[c].w * q4[c].w;
      #pragma unroll
      for (int off = 16; off >= 1; off >>= 1)
        pp += __shfl_xor(pp, off);   // head h = c*8 + (t>>5), dot over 32 lanes
      float w = __expf(pp * SCALE);
      accx[c] += w * vc[c].x; accy[c] += w * vc[c].y;
      accz[c] += w * vc[c].z; accw[c] += w * vc[c].w;
      if ((t & 31) == 0) wlds[(s << 5) + (c << 3) + (t >> 5)] = w;
      nz = nz || vc[c].x != 0.f || vc[c].y != 0.f || vc[c].z != 0.f || vc[c].w != 0.f;
    }
    unsigned long long b = __ballot(nz);
    if ((t & 63) == 0 && b != 0ULL) atomicOr(&flags[s], 1);
    #pragma unroll
    for (int c = 0; c < 4; ++c) { kc[c] = kn[c]; vc[c] = vn[c]; }
  }
  float* num = ws + WS_NUMP + (rep << 12);
  #pragma unroll
  for (int c = 0; c < 4; ++c) {
    int e = (c << 10) + (t << 2);
    atomicAdd(num + e + 0, accx[c]);
    atomicAdd(num + e + 1, accy[c]);
    atomicAdd(num + e + 2, accz[c]);
    atomicAdd(num + e + 3, accw[c]);
  }
  __syncthreads();   // wlds + flags complete
  if (t < 32) {
    float d = 0.f;
    #pragma unroll
    for (int s = 0; s < SLOTS; ++s)
      if (flags[s]) d += wlds[(s << 5) + t];
    atomicAdd(ws + WS_DENP + (rep << 6) + t, d);
  }
}

// ---------------- K4: write new-token row into both caches ------------------
__global__ __launch_bounds__(256) void lastslot(const float* __restrict__ ws,
    float* __restrict__ kout, float* __restrict__ vout) {
  int idx = (blockIdx.x * 256 + threadIdx.x) << 2;   // 8 blocks -> 8192 floats
  if (idx < E) {
    fv4 k = *reinterpret_cast<const fv4*>(ws + WS_KFIN + idx);
    ntstore4(kout + (size_t)(L - 1) * E + idx, k);
  } else {
    fv4 v = *reinterpret_cast<const fv4*>(ws + WS_VFIN + idx - E);
    ntstore4(vout + (size_t)(L - 1) * E + idx - E, v);
  }
}

// ---------------- K5: output GEMV with merge folded in; exclusive partials --
__global__ __launch_bounds__(256) void gemv_out(const float* __restrict__ Wo,
    const float* __restrict__ bo, float* __restrict__ ws) {
  int b = blockIdx.x;            // 256 blocks: 64 i-chunks x 4 col-groups
  int chunk = b >> 2;
  int g = b & 3;
  int t = threadIdx.x;
  int j = (g << 10) + (t << 2);
  __shared__ float vals[64];
  int i0 = chunk << 6;
  if (t < 64) {
    float s = 0.f;
    #pragma unroll
    for (int r = 0; r < 16; ++r) s += ws[WS_NUMP + (r << 12) + i0 + t];
    float d = 0.f;
    int h = chunk >> 1;
    #pragma unroll
    for (int r = 0; r < 16; ++r) d += ws[WS_DENP + (r << 6) + h];
    vals[t] = s / d;
  }
  __syncthreads();
  float ax = 0.f, ay = 0.f, az = 0.f, aw = 0.f;
  #pragma unroll 4
  for (int r = 0; r < 64; ++r) {
    int i = i0 + r;
    float vi = vals[r];
    const fv4 w4 = ntload4(Wo + (size_t)i * E + j);
    ax += vi * w4.x; ay += vi * w4.y; az += vi * w4.z; aw += vi * w4.w;
  }
  if (chunk == 0) {
    const fv4 b4 = *reinterpret_cast<const fv4*>(bo + j);
    ax += b4.x; ay += b4.y; az += b4.z; aw += b4.w;
  }
  fv4 val = {ax, ay, az, aw};
  ntstore4(ws + WS_OPART + (chunk << 12) + j, val);
}

// ---------------- K6: final out_i = sum of 64 chunk partials -----------------
__global__ __launch_bounds__(256) void writeout(const float* __restrict__ ws,
                                                float* __restrict__ out) {
  int i = blockIdx.x * 256 + threadIdx.x;   // 16 blocks
  float s = 0.f;
  #pragma unroll 8
  for (int c = 0; c < 64; ++c) s += ws[WS_OPART + (c << 12) + i];
  out[i] = s;
}

extern "C" void kernel_launch(void* const* d_in, const int* in_sizes, int n_in,
                              void* d_out, int out_size, void* d_ws, size_t ws_size,
                              hipStream_t stream) {
  const float* x   = (const float*)d_in[0];
  const float* vin = (const float*)d_in[1];
  const float* kin = (const float*)d_in[2];
  const float* Wv  = (const float*)d_in[3];
  const float* bv  = (const float*)d_in[4];
  const float* Wq  = (const float*)d_in[5];
  const float* bq  = (const float*)d_in[6];
  const float* Wk  = (const float*)d_in[7];
  const float* bk  = (const float*)d_in[8];
  const float* Wo  = (const float*)d_in[9];
  const float* bo  = (const float*)d_in[10];
  float* out  = (float*)d_out;
  float* vout = out + E;
  float* kout = vout + (size_t)L * E;
  float* ws   = (float*)d_ws;

  zero_np<<<(WS_OPART - WS_NUMP + 255) / 256, 256, 0, stream>>>(ws);
  gemv_qkv<<<384, 256, 0, stream>>>(x, Wq, Wk, Wv, ws);
  qkvred<<<48, 256, 0, stream>>>(bq, bk, bv, ws);
  attn<<<L / SLOTS, 256, 0, stream>>>(kin, vin, ws);
  // rolling-cache shift via runtime blit (reads may hit attn-warmed L3)
  hipMemcpyAsync(vout, vin + E, (size_t)(L - 1) * E * sizeof(float),
                 hipMemcpyDeviceToDevice, stream);
  hipMemcpyAsync(kout, kin + E, (size_t)(L - 1) * E * sizeof(float),
                 hipMemcpyDeviceToDevice, stream);
  lastslot<<<8, 256, 0, stream>>>(ws, kout, vout);
  gemv_out<<<256, 256, 0, stream>>>(Wo, bo, ws);
  writeout<<<16, 256, 0, stream>>>(ws, out);
}

// Round 15
// 224.583 us; speedup vs baseline: 1.1529x; 1.1529x over previous
//
#include <hip/hip_runtime.h>

#define E 4096
#define H 32
#define L 8192
#define SCALE 0.08838834764831845f  // 1/sqrt(128)

// workspace layout (float offsets); total 734208 floats = 2.9 MB
#define WS_PART  0            // [3][32][4096] exclusive qkv partials
#define WS_QFIN  393216       // 4096 (bias included)
#define WS_KFIN  397312       // 4096 (bias included)
#define WS_VFIN  401408       // 4096 (bias included)
#define WS_NUMP  405504       // 16 reps x 4096 (zeroed)
#define WS_DENP  471040       // 16 reps x 64   (zeroed)
#define WS_OPART 472064       // [64][4096] exclusive gemv_out partials

typedef float fv4 __attribute__((ext_vector_type(4)));

__device__ __forceinline__ fv4 ntload4(const float* p) {
  return __builtin_nontemporal_load(reinterpret_cast<const fv4*>(p));
}
__device__ __forceinline__ void ntstore4(float* p, fv4 v) {
  __builtin_nontemporal_store(v, reinterpret_cast<fv4*>(p));
}

// ---------------- K0: zero NUMP/DENP only (66560 floats) --------------------
__global__ __launch_bounds__(256) void zero_np(float* __restrict__ ws) {
  int i = blockIdx.x * 256 + threadIdx.x;
  if (i < (WS_OPART - WS_NUMP)) ws[WS_NUMP + i] = 0.f;
}

// ---------------- K1: q/k/v GEMV, exclusive NT partials (no atomics) --------
__global__ __launch_bounds__(256) void gemv_qkv(const float* __restrict__ x,
    const float* __restrict__ Wq, const float* __restrict__ Wk,
    const float* __restrict__ Wv, float* __restrict__ ws) {
  int b = blockIdx.x;            // 384 blocks: 3 mats x 32 chunks x 4 col-groups
  int mat = b >> 7;
  int rem = b & 127;
  int chunk = rem >> 2;          // 32 chunks of 128 rows
  int g = rem & 3;               // 4 col groups of 1024
  const float* W = (mat == 0) ? Wq : (mat == 1) ? Wk : Wv;
  int t = threadIdx.x;
  int j = (g << 10) + (t << 2);
  float ax = 0.f, ay = 0.f, az = 0.f, aw = 0.f;
  int i0 = chunk << 7;
  #pragma unroll 8
  for (int r = 0; r < 128; ++r) {
    int i = i0 + r;
    float xi = x[i];
    const fv4 w4 = ntload4(W + (size_t)i * E + j);
    ax += xi * w4.x; ay += xi * w4.y; az += xi * w4.z; aw += xi * w4.w;
  }
  fv4 val = {ax, ay, az, aw};
  ntstore4(ws + WS_PART + (mat << 17) + (chunk << 12) + j, val);
}

// ---------------- K2: reduce 32 chunk-partials, fold in biases --------------
__global__ __launch_bounds__(256) void qkvred(const float* __restrict__ bq,
    const float* __restrict__ bk, const float* __restrict__ bv,
    float* __restrict__ ws) {
  int e = blockIdx.x * 256 + threadIdx.x;   // 48 blocks, e in [0,12288)
  int mat = e >> 12;
  int col = e & 4095;
  const float* part = ws + WS_PART + (mat << 17);
  float s = 0.f;
  #pragma unroll 8
  for (int c = 0; c < 32; ++c) s += part[(c << 12) + col];
  const float* bias = (mat == 0) ? bq : (mat == 1) ? bk : bv;
  ws[WS_QFIN + (mat << 12) + col] = s + bias[col];
}

// ---------------- K3: READ-ONLY attention pass (NT loads, no stores) --------
#define SLOTS 16
__device__ __forceinline__ void load_slot(int o, int t,
    const float* __restrict__ kin, const float* __restrict__ vin,
    const float* __restrict__ ws, fv4 k4[4], fv4 v4[4]) {
  if (o < L - 1) {
    const float* ks = kin + (size_t)(o + 1) * E;
    const float* vs = vin + (size_t)(o + 1) * E;
    #pragma unroll
    for (int c = 0; c < 4; ++c) {
      int e = (c << 10) + (t << 2);
      k4[c] = ntload4(ks + e);
      v4[c] = ntload4(vs + e);
    }
  } else {
    #pragma unroll
    for (int c = 0; c < 4; ++c) {
      int e = (c << 10) + (t << 2);
      k4[c] = *reinterpret_cast<const fv4*>(ws + WS_KFIN + e);
      v4[c] = *reinterpret_cast<const fv4*>(ws + WS_VFIN + e);
    }
  }
}

__global__ __launch_bounds__(256) void attn(const float* __restrict__ kin,
    const float* __restrict__ vin, float* __restrict__ ws) {
  __shared__ float wlds[SLOTS * 32];
  __shared__ int flags[SLOTS];
  int t = threadIdx.x;
  if (t < SLOTS) flags[t] = 0;
  // q in registers (bias already folded in by qkvred)
  fv4 q4[4];
  #pragma unroll
  for (int c = 0; c < 4; ++c)
    q4[c] = *reinterpret_cast<const fv4*>(ws + WS_QFIN + (c << 10) + (t << 2));
  __syncthreads();   // flags init visible

  float accx[4] = {0,0,0,0}, accy[4] = {0,0,0,0};
  float accz[4] = {0,0,0,0}, accw[4] = {0,0,0,0};
  int base = blockIdx.x * SLOTS;
  int rep = blockIdx.x & 15;

  fv4 kc[4], vc[4], kn[4], vn[4];
  load_slot(base, t, kin, vin, ws, kc, vc);

  for (int s = 0; s < SLOTS; ++s) {
    int o = base + s;
    if (s + 1 < SLOTS)
      load_slot(o + 1, t, kin, vin, ws, kn, vn);
    bool nz = false;
    #pragma unroll
    for (int c = 0; c < 4; ++c) {
      float pp = kc[c].x * q4[c].x + kc[c].y * q4[c].y +
                 kc[c].z * q4[c].z + kc[c].w * q4[c].w;
      #pragma unroll
      for (int off = 16; off >= 1; off >>= 1)
        pp += __shfl_xor(pp, off);   // head h = c*8 + (t>>5), dot over 32 lanes
      float w = __expf(pp * SCALE);
      accx[c] += w * vc[c].x; accy[c] += w * vc[c].y;
      accz[c] += w * vc[c].z; accw[c] += w * vc[c].w;
      if ((t & 31) == 0) wlds[(s << 5) + (c << 3) + (t >> 5)] = w;
      nz = nz || vc[c].x != 0.f || vc[c].y != 0.f || vc[c].z != 0.f || vc[c].w != 0.f;
    }
    unsigned long long b = __ballot(nz);
    if ((t & 63) == 0 && b != 0ULL) atomicOr(&flags[s], 1);
    #pragma unroll
    for (int c = 0; c < 4; ++c) { kc[c] = kn[c]; vc[c] = vn[c]; }
  }
  float* num = ws + WS_NUMP + (rep << 12);
  #pragma unroll
  for (int c = 0; c < 4; ++c) {
    int e = (c << 10) + (t << 2);
    atomicAdd(num + e + 0, accx[c]);
    atomicAdd(num + e + 1, accy[c]);
    atomicAdd(num + e + 2, accz[c]);
    atomicAdd(num + e + 3, accw[c]);
  }
  __syncthreads();   // wlds + flags complete
  if (t < 32) {
    float d = 0.f;
    #pragma unroll
    for (int s = 0; s < SLOTS; ++s)
      if (flags[s]) d += wlds[(s << 5) + t];
    atomicAdd(ws + WS_DENP + (rep << 6) + t, d);
  }
}

// ---------------- K4: high-TLP grid-stride NT copy of the cache shift -------
#define N4 (((size_t)(L - 1) * E) >> 2)   // fv4 elements per stream
#define CPB 2048                          // blocks per stream
__global__ __launch_bounds__(256) void copykv(const float* __restrict__ kin,
    const float* __restrict__ vin, float* __restrict__ kout,
    float* __restrict__ vout) {
  int b = blockIdx.x;
  const fv4* src;
  fv4* dst;
  if (b < CPB) {
    src = reinterpret_cast<const fv4*>(kin + E);
    dst = reinterpret_cast<fv4*>(kout);
  } else {
    src = reinterpret_cast<const fv4*>(vin + E);
    dst = reinterpret_cast<fv4*>(vout);
    b -= CPB;
  }
  size_t stride = (size_t)CPB * 256;
  for (size_t i = (size_t)b * 256 + threadIdx.x; i < N4; i += stride)
    __builtin_nontemporal_store(__builtin_nontemporal_load(src + i), dst + i);
}

// ---------------- K5: write new-token row into both caches ------------------
__global__ __launch_bounds__(256) void lastslot(const float* __restrict__ ws,
    float* __restrict__ kout, float* __restrict__ vout) {
  int idx = (blockIdx.x * 256 + threadIdx.x) << 2;   // 8 blocks -> 8192 floats
  if (idx < E) {
    fv4 k = *reinterpret_cast<const fv4*>(ws + WS_KFIN + idx);
    ntstore4(kout + (size_t)(L - 1) * E + idx, k);
  } else {
    fv4 v = *reinterpret_cast<const fv4*>(ws + WS_VFIN + idx - E);
    ntstore4(vout + (size_t)(L - 1) * E + idx - E, v);
  }
}

// ---------------- K6: output GEMV with merge folded in; exclusive partials --
__global__ __launch_bounds__(256) void gemv_out(const float* __restrict__ Wo,
    const float* __restrict__ bo, float* __restrict__ ws) {
  int b = blockIdx.x;            // 256 blocks: 64 i-chunks x 4 col-groups
  int chunk = b >> 2;
  int g = b & 3;
  int t = threadIdx.x;
  int j = (g << 10) + (t << 2);
  __shared__ float vals[64];
  int i0 = chunk << 6;
  if (t < 64) {
    float s = 0.f;
    #pragma unroll
    for (int r = 0; r < 16; ++r) s += ws[WS_NUMP + (r << 12) + i0 + t];
    float d = 0.f;
    int h = chunk >> 1;
    #pragma unroll
    for (int r = 0; r < 16; ++r) d += ws[WS_DENP + (r << 6) + h];
    vals[t] = s / d;
  }
  __syncthreads();
  float ax = 0.f, ay = 0.f, az = 0.f, aw = 0.f;
  #pragma unroll 4
  for (int r = 0; r < 64; ++r) {
    int i = i0 + r;
    float vi = vals[r];
    const fv4 w4 = ntload4(Wo + (size_t)i * E + j);
    ax += vi * w4.x; ay += vi * w4.y; az += vi * w4.z; aw += vi * w4.w;
  }
  if (chunk == 0) {
    const fv4 b4 = *reinterpret_cast<const fv4*>(bo + j);
    ax += b4.x; ay += b4.y; az += b4.z; aw += b4.w;
  }
  fv4 val = {ax, ay, az, aw};
  ntstore4(ws + WS_OPART + (chunk << 12) + j, val);
}

// ---------------- K7: final out_i = sum of 64 chunk partials -----------------
__global__ __launch_bounds__(256) void writeout(const float* __restrict__ ws,
                                                float* __restrict__ out) {
  int i = blockIdx.x * 256 + threadIdx.x;   // 16 blocks
  float s = 0.f;
  #pragma unroll 8
  for (int c = 0; c < 64; ++c) s += ws[WS_OPART + (c << 12) + i];
  out[i] = s;
}

extern "C" void kernel_launch(void* const* d_in, const int* in_sizes, int n_in,
                              void* d_out, int out_size, void* d_ws, size_t ws_size,
                              hipStream_t stream) {
  const float* x   = (const float*)d_in[0];
  const float* vin = (const float*)d_in[1];
  const float* kin = (const float*)d_in[2];
  const float* Wv  = (const float*)d_in[3];
  const float* bv  = (const float*)d_in[4];
  const float* Wq  = (const float*)d_in[5];
  const float* bq  = (const float*)d_in[6];
  const float* Wk  = (const float*)d_in[7];
  const float* bk  = (const float*)d_in[8];
  const float* Wo  = (const float*)d_in[9];
  const float* bo  = (const float*)d_in[10];
  float* out  = (float*)d_out;
  float* vout = out + E;
  float* kout = vout + (size_t)L * E;
  float* ws   = (float*)d_ws;

  zero_np<<<(WS_OPART - WS_NUMP + 255) / 256, 256, 0, stream>>>(ws);
  gemv_qkv<<<384, 256, 0, stream>>>(x, Wq, Wk, Wv, ws);
  qkvred<<<48, 256, 0, stream>>>(bq, bk, bv, ws);
  attn<<<L / SLOTS, 256, 0, stream>>>(kin, vin, ws);
  copykv<<<2 * CPB, 256, 0, stream>>>(kin, vin, kout, vout);
  lastslot<<<8, 256, 0, stream>>>(ws, kout, vout);
  gemv_out<<<256, 256, 0, stream>>>(Wo, bo, ws);
  writeout<<<16, 256, 0, stream>>>(ws, out);
}

// Round 16
// 194.110 us; speedup vs baseline: 1.3339x; 1.1570x over previous
//
#include <hip/hip_runtime.h>

#define E 4096
#define H 32
#define L 8192
#define SCALE 0.08838834764831845f  // 1/sqrt(128)

// workspace layout (float offsets); total 734208 floats = 2.9 MB
#define WS_PART  0            // [3][32][4096] exclusive qkv partials
#define WS_QFIN  393216       // 4096 (bias included)
#define WS_KFIN  397312       // 4096 (bias included)
#define WS_VFIN  401408       // 4096 (bias included)
#define WS_NUMP  405504       // 16 reps x 4096 (zeroed)
#define WS_DENP  471040       // 16 reps x 64   (zeroed)
#define WS_OPART 472064       // [64][4096] exclusive gemv_out partials

typedef float fv4 __attribute__((ext_vector_type(4)));

__device__ __forceinline__ fv4 ntload4(const float* p) {
  return __builtin_nontemporal_load(reinterpret_cast<const fv4*>(p));
}
__device__ __forceinline__ void ntstore4(float* p, fv4 v) {
  __builtin_nontemporal_store(v, reinterpret_cast<fv4*>(p));
}

// ---------------- K0: zero NUMP/DENP only (66560 floats) --------------------
__global__ __launch_bounds__(256) void zero_np(float* __restrict__ ws) {
  int i = blockIdx.x * 256 + threadIdx.x;
  if (i < (WS_OPART - WS_NUMP)) ws[WS_NUMP + i] = 0.f;
}

// ---------------- K1: q/k/v GEMV, exclusive NT partials (no atomics) --------
__global__ __launch_bounds__(256) void gemv_qkv(const float* __restrict__ x,
    const float* __restrict__ Wq, const float* __restrict__ Wk,
    const float* __restrict__ Wv, float* __restrict__ ws) {
  int b = blockIdx.x;            // 384 blocks: 3 mats x 32 chunks x 4 col-groups
  int mat = b >> 7;
  int rem = b & 127;
  int chunk = rem >> 2;          // 32 chunks of 128 rows
  int g = rem & 3;               // 4 col groups of 1024
  const float* W = (mat == 0) ? Wq : (mat == 1) ? Wk : Wv;
  int t = threadIdx.x;
  int j = (g << 10) + (t << 2);
  float ax = 0.f, ay = 0.f, az = 0.f, aw = 0.f;
  int i0 = chunk << 7;
  #pragma unroll 8
  for (int r = 0; r < 128; ++r) {
    int i = i0 + r;
    float xi = x[i];
    const fv4 w4 = ntload4(W + (size_t)i * E + j);
    ax += xi * w4.x; ay += xi * w4.y; az += xi * w4.z; aw += xi * w4.w;
  }
  fv4 val = {ax, ay, az, aw};
  ntstore4(ws + WS_PART + (mat << 17) + (chunk << 12) + j, val);
}

// ---------------- K2: reduce 32 chunk-partials, fold in biases --------------
__global__ __launch_bounds__(256) void qkvred(const float* __restrict__ bq,
    const float* __restrict__ bk, const float* __restrict__ bv,
    float* __restrict__ ws) {
  int e = blockIdx.x * 256 + threadIdx.x;   // 48 blocks, e in [0,12288)
  int mat = e >> 12;
  int col = e & 4095;
  const float* part = ws + WS_PART + (mat << 17);
  float s = 0.f;
  #pragma unroll 8
  for (int c = 0; c < 32; ++c) s += part[(c << 12) + col];
  const float* bias = (mat == 0) ? bq : (mat == 1) ? bk : bv;
  ws[WS_QFIN + (mat << 12) + col] = s + bias[col];
}

// ---------------- K3: fused k+v shift + logits + accumulation ---------------
// R13 verbatim EXCEPT: cache-shift stores are PLAIN (retire in L2, drain via
// writeback) while loads stay NT (don't pollute L2/L3 weight residency).
#define SLOTS 16
__device__ __forceinline__ void load_slot(int o, int t,
    const float* __restrict__ kin, const float* __restrict__ vin,
    const float* __restrict__ ws, fv4 k4[4], fv4 v4[4]) {
  if (o < L - 1) {
    const float* ks = kin + (size_t)(o + 1) * E;
    const float* vs = vin + (size_t)(o + 1) * E;
    #pragma unroll
    for (int c = 0; c < 4; ++c) {
      int e = (c << 10) + (t << 2);
      k4[c] = ntload4(ks + e);
      v4[c] = ntload4(vs + e);
    }
  } else {
    #pragma unroll
    for (int c = 0; c < 4; ++c) {
      int e = (c << 10) + (t << 2);
      k4[c] = *reinterpret_cast<const fv4*>(ws + WS_KFIN + e);
      v4[c] = *reinterpret_cast<const fv4*>(ws + WS_VFIN + e);
    }
  }
}

__global__ __launch_bounds__(256) void kvpass(const float* __restrict__ kin,
    const float* __restrict__ vin,
    float* __restrict__ kout, float* __restrict__ vout,
    float* __restrict__ ws) {
  __shared__ float wlds[SLOTS * 32];
  __shared__ int flags[SLOTS];
  int t = threadIdx.x;
  if (t < SLOTS) flags[t] = 0;
  // q in registers (bias already folded in by qkvred)
  fv4 q4[4];
  #pragma unroll
  for (int c = 0; c < 4; ++c)
    q4[c] = *reinterpret_cast<const fv4*>(ws + WS_QFIN + (c << 10) + (t << 2));
  __syncthreads();   // flags init visible

  float accx[4] = {0,0,0,0}, accy[4] = {0,0,0,0};
  float accz[4] = {0,0,0,0}, accw[4] = {0,0,0,0};
  int base = blockIdx.x * SLOTS;
  int rep = blockIdx.x & 15;

  fv4 kc[4], vc[4], kn[4], vn[4];
  load_slot(base, t, kin, vin, ws, kc, vc);

  for (int s = 0; s < SLOTS; ++s) {
    int o = base + s;
    if (s + 1 < SLOTS)
      load_slot(o + 1, t, kin, vin, ws, kn, vn);
    float* kd = kout + (size_t)o * E;
    float* vd = vout + (size_t)o * E;
    #pragma unroll
    for (int c = 0; c < 4; ++c) {
      int e = (c << 10) + (t << 2);
      *reinterpret_cast<fv4*>(kd + e) = kc[c];   // plain store (L2)
      *reinterpret_cast<fv4*>(vd + e) = vc[c];   // plain store (L2)
    }
    bool nz = false;
    #pragma unroll
    for (int c = 0; c < 4; ++c) {
      float pp = kc[c].x * q4[c].x + kc[c].y * q4[c].y +
                 kc[c].z * q4[c].z + kc[c].w * q4[c].w;
      #pragma unroll
      for (int off = 16; off >= 1; off >>= 1)
        pp += __shfl_xor(pp, off);   // head h = c*8 + (t>>5), dot over 32 lanes
      float w = __expf(pp * SCALE);
      accx[c] += w * vc[c].x; accy[c] += w * vc[c].y;
      accz[c] += w * vc[c].z; accw[c] += w * vc[c].w;
      if ((t & 31) == 0) wlds[(s << 5) + (c << 3) + (t >> 5)] = w;
      nz = nz || vc[c].x != 0.f || vc[c].y != 0.f || vc[c].z != 0.f || vc[c].w != 0.f;
    }
    unsigned long long b = __ballot(nz);
    if ((t & 63) == 0 && b != 0ULL) atomicOr(&flags[s], 1);
    #pragma unroll
    for (int c = 0; c < 4; ++c) { kc[c] = kn[c]; vc[c] = vn[c]; }
  }
  float* num = ws + WS_NUMP + (rep << 12);
  #pragma unroll
  for (int c = 0; c < 4; ++c) {
    int e = (c << 10) + (t << 2);
    atomicAdd(num + e + 0, accx[c]);
    atomicAdd(num + e + 1, accy[c]);
    atomicAdd(num + e + 2, accz[c]);
    atomicAdd(num + e + 3, accw[c]);
  }
  __syncthreads();   // wlds + flags complete
  if (t < 32) {
    float d = 0.f;
    #pragma unroll
    for (int s = 0; s < SLOTS; ++s)
      if (flags[s]) d += wlds[(s << 5) + t];
    atomicAdd(ws + WS_DENP + (rep << 6) + t, d);
  }
}

// ---------------- K4: output GEMV with merge folded in; exclusive partials --
__global__ __launch_bounds__(256) void gemv_out(const float* __restrict__ Wo,
    const float* __restrict__ bo, float* __restrict__ ws) {
  int b = blockIdx.x;            // 256 blocks: 64 i-chunks x 4 col-groups
  int chunk = b >> 2;
  int g = b & 3;
  int t = threadIdx.x;
  int j = (g << 10) + (t << 2);
  __shared__ float vals[64];
  int i0 = chunk << 6;
  if (t < 64) {
    float s = 0.f;
    #pragma unroll
    for (int r = 0; r < 16; ++r) s += ws[WS_NUMP + (r << 12) + i0 + t];
    float d = 0.f;
    int h = chunk >> 1;
    #pragma unroll
    for (int r = 0; r < 16; ++r) d += ws[WS_DENP + (r << 6) + h];
    vals[t] = s / d;
  }
  __syncthreads();
  float ax = 0.f, ay = 0.f, az = 0.f, aw = 0.f;
  #pragma unroll 4
  for (int r = 0; r < 64; ++r) {
    int i = i0 + r;
    float vi = vals[r];
    const fv4 w4 = ntload4(Wo + (size_t)i * E + j);
    ax += vi * w4.x; ay += vi * w4.y; az += vi * w4.z; aw += vi * w4.w;
  }
  if (chunk == 0) {
    const fv4 b4 = *reinterpret_cast<const fv4*>(bo + j);
    ax += b4.x; ay += b4.y; az += b4.z; aw += b4.w;
  }
  fv4 val = {ax, ay, az, aw};
  ntstore4(ws + WS_OPART + (chunk << 12) + j, val);
}

// ---------------- K5: final out_i = sum of 64 chunk partials -----------------
__global__ __launch_bounds__(256) void writeout(const float* __restrict__ ws,
                                                float* __restrict__ out) {
  int i = blockIdx.x * 256 + threadIdx.x;   // 16 blocks
  float s = 0.f;
  #pragma unroll 8
  for (int c = 0; c < 64; ++c) s += ws[WS_OPART + (c << 12) + i];
  out[i] = s;
}

extern "C" void kernel_launch(void* const* d_in, const int* in_sizes, int n_in,
                              void* d_out, int out_size, void* d_ws, size_t ws_size,
                              hipStream_t stream) {
  const float* x   = (const float*)d_in[0];
  const float* vin = (const float*)d_in[1];
  const float* kin = (const float*)d_in[2];
  const float* Wv  = (const float*)d_in[3];
  const float* bv  = (const float*)d_in[4];
  const float* Wq  = (const float*)d_in[5];
  const float* bq  = (const float*)d_in[6];
  const float* Wk  = (const float*)d_in[7];
  const float* bk  = (const float*)d_in[8];
  const float* Wo  = (const float*)d_in[9];
  const float* bo  = (const float*)d_in[10];
  float* out  = (float*)d_out;
  float* vout = out + E;
  float* kout = vout + (size_t)L * E;
  float* ws   = (float*)d_ws;

  zero_np<<<(WS_OPART - WS_NUMP + 255) / 256, 256, 0, stream>>>(ws);
  gemv_qkv<<<384, 256, 0, stream>>>(x, Wq, Wk, Wv, ws);
  qkvred<<<48, 256, 0, stream>>>(bq, bk, bv, ws);
  kvpass<<<L / SLOTS, 256, 0, stream>>>(kin, vin, kout, vout, ws);
  gemv_out<<<256, 256, 0, stream>>>(Wo, bo, ws);
  writeout<<<16, 256, 0, stream>>>(ws, out);
}

// Round 17
// 168.308 us; speedup vs baseline: 1.5384x; 1.1533x over previous
//
#include <hip/hip_runtime.h>

#define E 4096
#define H 32
#define L 8192
#define SCALE 0.08838834764831845f  // 1/sqrt(128)

// workspace layout (float offsets); total 734208 floats = 2.9 MB
#define WS_PART  0            // [3][32][4096] exclusive qkv partials
#define WS_QFIN  393216       // 4096 (bias included)
#define WS_KFIN  397312       // 4096 (bias included)
#define WS_VFIN  401408       // 4096 (bias included)
#define WS_NUMP  405504       // 16 reps x 4096 (zeroed)
#define WS_DENP  471040       // 16 reps x 64   (zeroed)
#define WS_OPART 472064       // [64][4096] exclusive gemv_out partials

typedef float fv4 __attribute__((ext_vector_type(4)));

__device__ __forceinline__ fv4 ntload4(const float* p) {
  return __builtin_nontemporal_load(reinterpret_cast<const fv4*>(p));
}
__device__ __forceinline__ void ntstore4(float* p, fv4 v) {
  __builtin_nontemporal_store(v, reinterpret_cast<fv4*>(p));
}

// ---------------- K0: zero NUMP/DENP only (66560 floats) --------------------
__global__ __launch_bounds__(256) void zero_np(float* __restrict__ ws) {
  int i = blockIdx.x * 256 + threadIdx.x;
  if (i < (WS_OPART - WS_NUMP)) ws[WS_NUMP + i] = 0.f;
}

// ---------------- K1: q/k/v GEMV, exclusive NT partials (no atomics) --------
__global__ __launch_bounds__(256) void gemv_qkv(const float* __restrict__ x,
    const float* __restrict__ Wq, const float* __restrict__ Wk,
    const float* __restrict__ Wv, float* __restrict__ ws) {
  int b = blockIdx.x;            // 384 blocks: 3 mats x 32 chunks x 4 col-groups
  int mat = b >> 7;
  int rem = b & 127;
  int chunk = rem >> 2;          // 32 chunks of 128 rows
  int g = rem & 3;               // 4 col groups of 1024
  const float* W = (mat == 0) ? Wq : (mat == 1) ? Wk : Wv;
  int t = threadIdx.x;
  int j = (g << 10) + (t << 2);
  float ax = 0.f, ay = 0.f, az = 0.f, aw = 0.f;
  int i0 = chunk << 7;
  #pragma unroll 8
  for (int r = 0; r < 128; ++r) {
    int i = i0 + r;
    float xi = x[i];
    const fv4 w4 = ntload4(W + (size_t)i * E + j);
    ax += xi * w4.x; ay += xi * w4.y; az += xi * w4.z; aw += xi * w4.w;
  }
  fv4 val = {ax, ay, az, aw};
  ntstore4(ws + WS_PART + (mat << 17) + (chunk << 12) + j, val);
}

// ---------------- K2: reduce 32 chunk-partials, fold in biases --------------
__global__ __launch_bounds__(256) void qkvred(const float* __restrict__ bq,
    const float* __restrict__ bk, const float* __restrict__ bv,
    float* __restrict__ ws) {
  int e = blockIdx.x * 256 + threadIdx.x;   // 48 blocks, e in [0,12288)
  int mat = e >> 12;
  int col = e & 4095;
  const float* part = ws + WS_PART + (mat << 17);
  float s = 0.f;
  #pragma unroll 8
  for (int c = 0; c < 32; ++c) s += part[(c << 12) + col];
  const float* bias = (mat == 0) ? bq : (mat == 1) ? bk : bv;
  ws[WS_QFIN + (mat << 12) + col] = s + bias[col];
}

// ---------------- K3: fused k+v shift + logits + accumulation ---------------
#define SLOTS 16
__device__ __forceinline__ void load_slot(int o, int t,
    const float* __restrict__ kin, const float* __restrict__ vin,
    const float* __restrict__ ws, fv4 k4[4], fv4 v4[4]) {
  if (o < L - 1) {
    const float* ks = kin + (size_t)(o + 1) * E;
    const float* vs = vin + (size_t)(o + 1) * E;
    #pragma unroll
    for (int c = 0; c < 4; ++c) {
      int e = (c << 10) + (t << 2);
      k4[c] = ntload4(ks + e);
      v4[c] = ntload4(vs + e);
    }
  } else {
    #pragma unroll
    for (int c = 0; c < 4; ++c) {
      int e = (c << 10) + (t << 2);
      k4[c] = *reinterpret_cast<const fv4*>(ws + WS_KFIN + e);
      v4[c] = *reinterpret_cast<const fv4*>(ws + WS_VFIN + e);
    }
  }
}

__global__ __launch_bounds__(256) void kvpass(const float* __restrict__ kin,
    const float* __restrict__ vin,
    float* __restrict__ kout, float* __restrict__ vout,
    float* __restrict__ ws) {
  __shared__ float wlds[SLOTS * 32];
  __shared__ int flags[SLOTS];
  int t = threadIdx.x;
  if (t < SLOTS) flags[t] = 0;
  // q in registers (bias already folded in by qkvred)
  fv4 q4[4];
  #pragma unroll
  for (int c = 0; c < 4; ++c)
    q4[c] = *reinterpret_cast<const fv4*>(ws + WS_QFIN + (c << 10) + (t << 2));
  __syncthreads();   // flags init visible

  float accx[4] = {0,0,0,0}, accy[4] = {0,0,0,0};
  float accz[4] = {0,0,0,0}, accw[4] = {0,0,0,0};
  int base = blockIdx.x * SLOTS;
  int rep = blockIdx.x & 15;

  fv4 kc[4], vc[4], kn[4], vn[4];
  load_slot(base, t, kin, vin, ws, kc, vc);

  for (int s = 0; s < SLOTS; ++s) {
    int o = base + s;
    if (s + 1 < SLOTS)
      load_slot(o + 1, t, kin, vin, ws, kn, vn);
    float* kd = kout + (size_t)o * E;
    float* vd = vout + (size_t)o * E;
    #pragma unroll
    for (int c = 0; c < 4; ++c) {
      int e = (c << 10) + (t << 2);
      ntstore4(kd + e, kc[c]);
      ntstore4(vd + e, vc[c]);
    }
    bool nz = false;
    #pragma unroll
    for (int c = 0; c < 4; ++c) {
      float pp = kc[c].x * q4[c].x + kc[c].y * q4[c].y +
                 kc[c].z * q4[c].z + kc[c].w * q4[c].w;
      #pragma unroll
      for (int off = 16; off >= 1; off >>= 1)
        pp += __shfl_xor(pp, off);   // head h = c*8 + (t>>5), dot over 32 lanes
      float w = __expf(pp * SCALE);
      accx[c] += w * vc[c].x; accy[c] += w * vc[c].y;
      accz[c] += w * vc[c].z; accw[c] += w * vc[c].w;
      if ((t & 31) == 0) wlds[(s << 5) + (c << 3) + (t >> 5)] = w;
      nz = nz || vc[c].x != 0.f || vc[c].y != 0.f || vc[c].z != 0.f || vc[c].w != 0.f;
    }
    unsigned long long b = __ballot(nz);
    if ((t & 63) == 0 && b != 0ULL) atomicOr(&flags[s], 1);
    #pragma unroll
    for (int c = 0; c < 4; ++c) { kc[c] = kn[c]; vc[c] = vn[c]; }
  }
  float* num = ws + WS_NUMP + (rep << 12);
  #pragma unroll
  for (int c = 0; c < 4; ++c) {
    int e = (c << 10) + (t << 2);
    atomicAdd(num + e + 0, accx[c]);
    atomicAdd(num + e + 1, accy[c]);
    atomicAdd(num + e + 2, accz[c]);
    atomicAdd(num + e + 3, accw[c]);
  }
  __syncthreads();   // wlds + flags complete
  if (t < 32) {
    float d = 0.f;
    #pragma unroll
    for (int s = 0; s < SLOTS; ++s)
      if (flags[s]) d += wlds[(s << 5) + t];
    atomicAdd(ws + WS_DENP + (rep << 6) + t, d);
  }
}

// ---------------- K4: output GEMV with merge folded in; exclusive partials --
__global__ __launch_bounds__(256) void gemv_out(const float* __restrict__ Wo,
    const float* __restrict__ bo, float* __restrict__ ws) {
  int b = blockIdx.x;            // 256 blocks: 64 i-chunks x 4 col-groups
  int chunk = b >> 2;
  int g = b & 3;
  int t = threadIdx.x;
  int j = (g << 10) + (t << 2);
  __shared__ float vals[64];
  int i0 = chunk << 6;
  if (t < 64) {
    float s = 0.f;
    #pragma unroll
    for (int r = 0; r < 16; ++r) s += ws[WS_NUMP + (r << 12) + i0 + t];
    float d = 0.f;
    int h = chunk >> 1;
    #pragma unroll
    for (int r = 0; r < 16; ++r) d += ws[WS_DENP + (r << 6) + h];
    vals[t] = s / d;
  }
  __syncthreads();
  float ax = 0.f, ay = 0.f, az = 0.f, aw = 0.f;
  #pragma unroll 4
  for (int r = 0; r < 64; ++r) {
    int i = i0 + r;
    float vi = vals[r];
    const fv4 w4 = ntload4(Wo + (size_t)i * E + j);
    ax += vi * w4.x; ay += vi * w4.y; az += vi * w4.z; aw += vi * w4.w;
  }
  if (chunk == 0) {
    const fv4 b4 = *reinterpret_cast<const fv4*>(bo + j);
    ax += b4.x; ay += b4.y; az += b4.z; aw += b4.w;
  }
  fv4 val = {ax, ay, az, aw};
  ntstore4(ws + WS_OPART + (chunk << 12) + j, val);
}

// ---------------- K5: final out_i = sum of 64 chunk partials -----------------
__global__ __launch_bounds__(256) void writeout(const float* __restrict__ ws,
                                                float* __restrict__ out) {
  int i = blockIdx.x * 256 + threadIdx.x;   // 16 blocks
  float s = 0.f;
  #pragma unroll 8
  for (int c = 0; c < 64; ++c) s += ws[WS_OPART + (c << 12) + i];
  out[i] = s;
}

extern "C" void kernel_launch(void* const* d_in, const int* in_sizes, int n_in,
                              void* d_out, int out_size, void* d_ws, size_t ws_size,
                              hipStream_t stream) {
  const float* x   = (const float*)d_in[0];
  const float* vin = (const float*)d_in[1];
  const float* kin = (const float*)d_in[2];
  const float* Wv  = (const float*)d_in[3];
  const float* bv  = (const float*)d_in[4];
  const float* Wq  = (const float*)d_in[5];
  const float* bq  = (const float*)d_in[6];
  const float* Wk  = (const float*)d_in[7];
  const float* bk  = (const float*)d_in[8];
  const float* Wo  = (const float*)d_in[9];
  const float* bo  = (const float*)d_in[10];
  float* out  = (float*)d_out;
  float* vout = out + E;
  float* kout = vout + (size_t)L * E;
  float* ws   = (float*)d_ws;

  zero_np<<<(WS_OPART - WS_NUMP + 255) / 256, 256, 0, stream>>>(ws);
  gemv_qkv<<<384, 256, 0, stream>>>(x, Wq, Wk, Wv, ws);
  qkvred<<<48, 256, 0, stream>>>(bq, bk, bv, ws);
  kvpass<<<L / SLOTS, 256, 0, stream>>>(kin, vin, kout, vout, ws);
  gemv_out<<<256, 256, 0, stream>>>(Wo, bo, ws);
  writeout<<<16, 256, 0, stream>>>(ws, out);
}